// Round 10
// baseline (2379.696 us; speedup 1.0000x reference)
//
#include <hip/hip_runtime.h>
#include <math.h>

// Whole sparse masked-3D-CNN pipeline in ONE persistent kernel (plain launch,
// 512 blocks x 256 thr; co-residency by occupancy arithmetic: LDS 17.4KB and
// __launch_bounds__(256,4) give >=4 blocks/CU >= the 2/CU required).
// B=2, S=128, N=60000. Levels: 0:128^3 1:64^3 2:32^3 3:16^3 4:8^3, pools 4^3,2^3.
// uint16 index grids (id<60000, 0xFFFF empty). Scans are "write-all"; idx grids
// pre-filled 0xAA by a memset node (0xAAAA != MARKV). Hand-rolled 2-level grid
// barrier (64-spread arrivals + master wave in block 0), init'd by 512B memset.

#define NPTS 60000
#define NB 2
#define NEGF -3.0e38f
#define EPSF 1.0e-4f
#define MARKV 0xFFFEu
#define EMPTYV 0xFFFFu
#define NSLOT 16
#define NBLK 512
#define NTHR 256

constexpr int NV0 = NB * 128 * 128 * 128;
constexpr int NV1 = NB * 64 * 64 * 64;
constexpr int NV2 = NB * 32 * 32 * 32;
constexpr int NV3 = NB * 16 * 16 * 16;
constexpr int NV4 = NB * 8 * 8 * 8;

// ---- workspace layout (bytes) ----
constexpr size_t OFF_CNT   = 0;       // int[16]
constexpr size_t OFF_BNSUM = 1024;    // float[4][NSLOT][64]
constexpr size_t OFF_BNSS  = 17408;   // float[4][NSLOT][64]
constexpr size_t OFF_MASK5 = 33792;   // int[128] -> ends 34304
constexpr size_t OFF_BAR   = 34304;   // unsigned[64] arrivals + go (512B, memset 0)
constexpr size_t OFF_FCOMP = 34816;   // float[NPTS]
constexpr size_t OFF_IDX0  = 294912;                       // u16[NV0]
constexpr size_t OFF_IDX1  = OFF_IDX0 + (size_t)NV0 * 2;
constexpr size_t OFF_IDX2  = OFF_IDX1 + (size_t)NV1 * 2;
constexpr size_t OFF_IDX3  = OFF_IDX2 + (size_t)NV2 * 2;
constexpr size_t OFF_IDX4  = OFF_IDX3 + (size_t)NV3 * 2;
constexpr size_t OFF_LIST0 = OFF_IDX4 + (size_t)NV4 * 2;
constexpr size_t OFF_LIST1 = OFF_LIST0 + (size_t)NPTS * 4;
constexpr size_t OFF_LIST2 = OFF_LIST1 + (size_t)NPTS * 4;
constexpr size_t OFF_LIST3 = OFF_LIST2 + (size_t)NPTS * 4;
constexpr size_t OFF_LIST4 = OFF_LIST3 + (size_t)NV3 * 4;
constexpr size_t OFF_H0 = OFF_LIST4 + (size_t)NV4 * 4;     // NPTS*8
constexpr size_t OFF_H1 = OFF_H0 + (size_t)NPTS * 8 * 4;   // NPTS*16
constexpr size_t OFF_H2 = OFF_H1 + (size_t)NPTS * 16 * 4;  // NPTS*32
constexpr size_t OFF_H3 = OFF_H2 + (size_t)NPTS * 32 * 4;  // NV3*64
constexpr size_t OFF_H4 = OFF_H3 + (size_t)NV3 * 64 * 4;   // dense [b][128][8^3]
constexpr size_t OFF_H5 = OFF_H4 + (size_t)NV4 * 128 * 4;  // [b][128][4^3]

// ---- grid barrier: 64-spread arrivals, block-0 wave masters, go-flag ----
__device__ __forceinline__ void gsync(unsigned* bar_arr, unsigned* bar_go,
                                      unsigned gen, int blk, int tid) {
  __threadfence();
  __syncthreads();
  if (tid == 0)
    __hip_atomic_fetch_add(&bar_arr[blk & 63], 1u, __ATOMIC_RELEASE,
                           __HIP_MEMORY_SCOPE_AGENT);
  if (blk == 0) {
    if (tid < 64) {
      unsigned target = gen * (unsigned)NBLK;
      while (true) {
        unsigned v = __hip_atomic_load(&bar_arr[tid], __ATOMIC_ACQUIRE,
                                       __HIP_MEMORY_SCOPE_AGENT);
        unsigned s = v;
#pragma unroll
        for (int off = 32; off; off >>= 1) s += __shfl_xor(s, off, 64);
        if (s >= target) break;
        __builtin_amdgcn_s_sleep(1);
      }
      if (tid == 0)
        __hip_atomic_store(bar_go, gen, __ATOMIC_RELEASE,
                           __HIP_MEMORY_SCOPE_AGENT);
    }
  } else if (tid == 0) {
    while (__hip_atomic_load(bar_go, __ATOMIC_ACQUIRE,
                             __HIP_MEMORY_SCOPE_AGENT) < gen)
      __builtin_amdgcn_s_sleep(2);
  }
  __syncthreads();
  __threadfence();
}

// ---- write-all block-scan compaction (marks -> contiguous ids) ----
template <int SL, int PBLK, int IT4, bool HASPAR>
__device__ __forceinline__ void cscan_phase(int blk, int tid,
                                            unsigned short* __restrict__ idx,
                                            int* __restrict__ list,
                                            int* __restrict__ cnt, int slot,
                                            unsigned short* __restrict__ idx_par,
                                            float* smem) {
  if (blk >= PBLK) return;
  int* sw = (int*)smem;  // [0..3]=wave totals/offsets, [4]=block base
  constexpr int NT = PBLK * NTHR;
  int t64 = blk * NTHR + tid;
  const ushort4* p4 = (const ushort4*)idx;
  int c = 0;
  ushort4 uu[IT4];
#pragma unroll
  for (int k = 0; k < IT4; k++) {
    uu[k] = p4[t64 + k * NT];
    c += (uu[k].x == MARKV) + (uu[k].y == MARKV) + (uu[k].z == MARKV) +
         (uu[k].w == MARKV);
  }
  int lane = tid & 63, wid = tid >> 6;
  int x = c;
#pragma unroll
  for (int off = 1; off < 64; off <<= 1) {
    int y = __shfl_up(x, off, 64);
    if (lane >= off) x += y;
  }
  if (lane == 63) sw[wid] = x;
  __syncthreads();
  if (tid == 0) {
    int r = 0;
#pragma unroll
    for (int wv = 0; wv < 4; wv++) { int t = sw[wv]; sw[wv] = r; r += t; }
    sw[4] = r ? atomicAdd(&cnt[slot], r) : 0;
  }
  __syncthreads();
  int my = sw[4] + sw[wid] + (x - c);
  ushort4* p4w = (ushort4*)idx;
#pragma unroll
  for (int k = 0; k < IT4; k++) {
    int i4 = t64 + k * NT;
    unsigned short in[4] = {uu[k].x, uu[k].y, uu[k].z, uu[k].w};
    unsigned short o[4];
#pragma unroll
    for (int j = 0; j < 4; j++) {
      if (in[j] == MARKV) {
        int v = i4 * 4 + j;
        o[j] = (unsigned short)my;
        list[my] = v;
        my++;
        if (HASPAR) {
          int z = v & (SL - 1), y = (v / SL) & (SL - 1),
              xx = (v / (SL * SL)) & (SL - 1), b = v / (SL * SL * SL);
          constexpr int SP = SL / 2;
          int pv = ((b * SP + (xx >> 1)) * SP + (y >> 1)) * SP + (z >> 1);
          idx_par[pv] = (unsigned short)MARKV;
        }
      } else {
        o[j] = (unsigned short)EMPTYV;
      }
    }
    p4w[i4] = make_ushort4(o[0], o[1], o[2], o[3]);
  }
}

// ---- stride-2 VALID 2^3 conv, grid-stride over (oc-group, parent-group) ----
template <int Ci, int Co, int OCCHUNK, int SLpar, int DENSE_OUT>
__device__ __forceinline__ void conv_loop(
    int first, int avail, int blk, int tid, const float* __restrict__ hin,
    const unsigned short* __restrict__ idxc, const int* __restrict__ listpar,
    const int* __restrict__ cnt, int slot_bn, int slot_par,
    const float* __restrict__ w, const float* __restrict__ bnsum_in,
    const float* __restrict__ bnss_in, const float* __restrict__ g,
    const float* __restrict__ beta, float* __restrict__ bnsum_out,
    float* __restrict__ bnss_out, float* __restrict__ hout, float* smem) {
  constexpr int TPP = OCCHUNK / 8;   // threads per parent
  constexpr int PPB = NTHR / TPP;    // parents per block
  constexpr int NOCG = Co / OCCHUNK;
  int n = cnt[slot_par];
  int npg = (n + PPB - 1) / PPB;
  int nitems = npg * NOCG;
  float* wl = smem;          // <= 4096 floats for all instantiations
  float* sl = smem + 4096;   // Ci <= 64
  float* bl = smem + 4160;
  float* bnl = smem + 4224;  // 2*OCCHUNK <= 64
  for (int item = first; item < nitems; item += avail) {
    int pg = item % npg;
    int ocbase = (item / npg) * OCCHUNK;
    __syncthreads();  // previous iteration's readers of wl are done
    for (int i = tid; i < Ci * 8 * OCCHUNK; i += NTHR) {
      int ol = i % OCCHUNK;
      int it = i / OCCHUNK;  // ci*8 + t
      int ci = it >> 3, t = it & 7;
      wl[i] = w[((size_t)(ocbase + ol) * Ci + ci) * 8 + t];
    }
    if (tid < Ci) {
      float nn = (float)cnt[slot_bn];
      float s = 0.f, ss = 0.f;
#pragma unroll
      for (int k = 0; k < NSLOT; k++) {
        s += bnsum_in[k * 64 + tid];
        ss += bnss_in[k * 64 + tid];
      }
      float mu = s / nn;
      float var = fmaxf(ss / nn - mu * mu, 0.f);
      float sc = g[tid] / sqrtf(var + EPSF);
      sl[tid] = sc;
      bl[tid] = beta[tid] - mu * sc;
    }
    if (!DENSE_OUT && tid < 2 * OCCHUNK) bnl[tid] = 0.f;
    __syncthreads();
    int pid = pg * PPB + tid / TPP;
    int og = tid % TPP;
    bool act = pid < n;
    float acc[8] = {0, 0, 0, 0, 0, 0, 0, 0};
    int Xc = 0, Yc = 0, Zc = 0, bb = 0;
    if (act) {
      int pv = listpar[pid];
      constexpr int SL = SLpar, SC = SLpar * 2;
      Zc = pv & (SL - 1);
      Yc = (pv / SL) & (SL - 1);
      Xc = (pv / (SL * SL)) & (SL - 1);
      bb = pv / (SL * SL * SL);
      for (int t = 0; t < 8; t++) {
        int kd = t >> 2, kh = (t >> 1) & 1, kw = t & 1;
        int cv = ((bb * SC + 2 * Xc + kd) * SC + 2 * Yc + kh) * SC + 2 * Zc + kw;
        unsigned e = idxc[cv];
        if (e >= 0xFFFEu) continue;  // empty child contributes 0
        const float* hp = hin + (size_t)e * Ci;
#pragma unroll
        for (int i = 0; i < Ci; i += 4) {
          float4 xv = *(const float4*)(hp + i);
          float y0 = fmaxf(fmaf(xv.x, sl[i + 0], bl[i + 0]), 0.f);
          float y1 = fmaxf(fmaf(xv.y, sl[i + 1], bl[i + 1]), 0.f);
          float y2 = fmaxf(fmaf(xv.z, sl[i + 2], bl[i + 2]), 0.f);
          float y3 = fmaxf(fmaf(xv.w, sl[i + 3], bl[i + 3]), 0.f);
          const float* wp0 = &wl[((i + 0) * 8 + t) * OCCHUNK + og * 8];
          const float* wp1 = &wl[((i + 1) * 8 + t) * OCCHUNK + og * 8];
          const float* wp2 = &wl[((i + 2) * 8 + t) * OCCHUNK + og * 8];
          const float* wp3 = &wl[((i + 3) * 8 + t) * OCCHUNK + og * 8];
#pragma unroll
          for (int o = 0; o < 8; o++) {
            acc[o] = fmaf(y0, wp0[o], acc[o]);
            acc[o] = fmaf(y1, wp1[o], acc[o]);
            acc[o] = fmaf(y2, wp2[o], acc[o]);
            acc[o] = fmaf(y3, wp3[o], acc[o]);
          }
        }
      }
      if (!DENSE_OUT) {
        float* op = hout + (size_t)pid * Co + ocbase + og * 8;
#pragma unroll
        for (int o = 0; o < 8; o++) op[o] = acc[o];
      } else {
        int sp = (Xc * 8 + Yc) * 8 + Zc;  // SLpar == 8
#pragma unroll
        for (int o = 0; o < 8; o++)
          hout[((size_t)bb * 128 + ocbase + og * 8 + o) * 512 + sp] = acc[o];
      }
    }
    if (!DENSE_OUT) {
      int lane = tid & 63;
#pragma unroll
      for (int o = 0; o < 8; o++) {
        float a = acc[o], q = a * a;
#pragma unroll
        for (int off = TPP; off < 64; off <<= 1) {
          a += __shfl_down(a, off, 64);
          q += __shfl_down(q, off, 64);
        }
        if (lane < TPP) {  // og == lane here
          atomicAdd(&bnl[lane * 8 + o], a);
          atomicAdd(&bnl[OCCHUNK + lane * 8 + o], q);
        }
      }
      __syncthreads();
      if (tid < OCCHUNK) {
        int s = (blk & (NSLOT - 1)) * 64;
        atomicAdd(&bnsum_out[s + ocbase + tid], bnl[tid]);
        atomicAdd(&bnss_out[s + ocbase + tid], bnl[OCCHUNK + tid]);
      }
    }
  }
}

// ---------------- the mega-kernel ----------------
__global__ __launch_bounds__(NTHR, 4) void k_all(
    const float* __restrict__ pc, const float* __restrict__ wsub,
    const float* __restrict__ w0, const float* __restrict__ w1,
    const float* __restrict__ w2, const float* __restrict__ w3,
    const float* __restrict__ g0, const float* __restrict__ g1,
    const float* __restrict__ g2, const float* __restrict__ g3,
    const float* __restrict__ b0, const float* __restrict__ b1,
    const float* __restrict__ b2, const float* __restrict__ b3,
    const float* __restrict__ Wc, const float* __restrict__ bcv,
    float* __restrict__ out, char* __restrict__ base) {
  __shared__ float smem[4352];  // 17408 B -> >=4 blocks/CU with VGPR<=128
  int blk = blockIdx.x, tid = threadIdx.x;

  int* cnt = (int*)(base + OFF_CNT);
  float* bnsum = (float*)(base + OFF_BNSUM);
  float* bnss = (float*)(base + OFF_BNSS);
  int* mask5 = (int*)(base + OFF_MASK5);
  unsigned* bar_arr = (unsigned*)(base + OFF_BAR);
  unsigned* bar_go = (unsigned*)(base + OFF_BAR + 256);
  float* fcomp = (float*)(base + OFF_FCOMP);
  unsigned short* idx0 = (unsigned short*)(base + OFF_IDX0);
  unsigned short* idx1 = (unsigned short*)(base + OFF_IDX1);
  unsigned short* idx2 = (unsigned short*)(base + OFF_IDX2);
  unsigned short* idx3 = (unsigned short*)(base + OFF_IDX3);
  unsigned short* idx4 = (unsigned short*)(base + OFF_IDX4);
  int* list0 = (int*)(base + OFF_LIST0);
  int* list1 = (int*)(base + OFF_LIST1);
  int* list2 = (int*)(base + OFF_LIST2);
  int* list3 = (int*)(base + OFF_LIST3);
  int* list4 = (int*)(base + OFF_LIST4);
  float* h0 = (float*)(base + OFF_H0);
  float* h1 = (float*)(base + OFF_H1);
  float* h2 = (float*)(base + OFF_H2);
  float* h3 = (float*)(base + OFF_H3);
  float* h4 = (float*)(base + OFF_H4);
  float* h5 = (float*)(base + OFF_H5);

  // ---- P1: clear cnt/bn/mask5/fcomp, mark idx0, write coords ----
  {
    int gid = blk * NTHR + tid;  // 131072 threads
    if (gid < 2112) ((int4*)base)[gid] = make_int4(0, 0, 0, 0);
    if (gid < 15000) ((float4*)fcomp)[gid] = make_float4(0.f, 0.f, 0.f, 0.f);
    if (gid < NPTS) {
      const float* p = pc + (size_t)gid * 5;
      float fb = p[0], fx = p[1], fy = p[2], fz = p[3];
      ((float4*)out)[gid] = make_float4(fb, fx, fy, fz);
      int b = (int)fb, xx = (int)fx, yy = (int)fy, zz = (int)fz;
      int v = ((b * 128 + xx) * 128 + yy) * 128 + zz;
      idx0[v] = (unsigned short)MARKV;
    }
  }
  gsync(bar_arr, bar_go, 1, blk, tid);

  // ---- P2: compact level 0 (write-all; marks idx1 parents) ----
  cscan_phase<128, 512, 8, true>(blk, tid, idx0, list0, cnt, 0, idx1, smem);
  gsync(bar_arr, bar_go, 2, blk, tid);

  // ---- P3: compact level 1 (blocks 0..63)  ||  point-feature scatter ----
  if (blk < 64) {
    cscan_phase<64, 64, 8, true>(blk, tid, idx1, list1, cnt, 1, idx2, smem);
  } else {
    int i = (blk - 64) * NTHR + tid;
    if (i < NPTS) {
      const float* p = pc + (size_t)i * 5;
      int b = (int)p[0], xx = (int)p[1], yy = (int)p[2], zz = (int)p[3];
      float f = p[4];
      int v = ((b * 128 + xx) * 128 + yy) * 128 + zz;
      unsigned e = idx0[v];
      atomicAdd(&fcomp[e], f);
    }
  }
  gsync(bar_arr, bar_go, 3, blk, tid);

  // ---- P4: compact level 2 (blocks 0..15)  ||  submanifold conv + BN0 ----
  if (blk < 16) {
    cscan_phase<32, 16, 4, true>(blk, tid, idx2, list2, cnt, 2, idx3, smem);
  } else {
    float* wl = smem;         // 216
    float* sbn = smem + 216;  // 16
    for (int i = tid; i < 216; i += NTHR) wl[i] = wsub[i];
    if (tid < 16) sbn[tid] = 0.f;
    __syncthreads();
    int n0 = cnt[0];
    int ngrp = (n0 + 63) >> 6;  // 64 points per group (4 threads/point)
    int sub = tid & 3;
    int lane = tid & 63;
    for (int grp = blk - 16; grp < ngrp; grp += (NBLK - 16)) {
      int pid = grp * 64 + (tid >> 2);
      bool act = pid < n0;
      float acc[8] = {0, 0, 0, 0, 0, 0, 0, 0};
      if (act) {
        int v = list0[pid];
        int z = v & 127, y = (v >> 7) & 127, x = (v >> 14) & 127, b = v >> 21;
        int t0 = sub * 7, t1 = t0 + 7 > 27 ? 27 : t0 + 7;
        for (int t = t0; t < t1; t++) {
          int kd = t / 9, kh = (t / 3) % 3, kw = t % 3;
          int xx = x + kd - 1, yy = y + kh - 1, zz = z + kw - 1;
          if ((unsigned)xx < 128u && (unsigned)yy < 128u &&
              (unsigned)zz < 128u) {
            unsigned e = idx0[((b * 128 + xx) * 128 + yy) * 128 + zz];
            if (e != EMPTYV) {
              float val = fcomp[e];
#pragma unroll
              for (int o = 0; o < 8; o++)
                acc[o] = fmaf(val, wl[o * 27 + t], acc[o]);
            }
          }
        }
      }
#pragma unroll
      for (int o = 0; o < 8; o++) {  // combine the 4 tap-groups
        acc[o] += __shfl_xor(acc[o], 1, 64);
        acc[o] += __shfl_xor(acc[o], 2, 64);
      }
      if (act)
        ((float2*)(h0 + (size_t)pid * 8))[sub] =
            make_float2(acc[sub * 2], acc[sub * 2 + 1]);
#pragma unroll
      for (int o = 0; o < 8; o++) {  // each point counted once per channel
        float a = ((o >> 1) == sub && act) ? acc[o] : 0.f;
        float q = a * a;
#pragma unroll
        for (int off = 32; off > 0; off >>= 1) {
          a += __shfl_down(a, off, 64);
          q += __shfl_down(q, off, 64);
        }
        if (lane == 0) {
          atomicAdd(&sbn[o], a);
          atomicAdd(&sbn[8 + o], q);
        }
      }
    }
    __syncthreads();
    if (tid < 8) {
      int s = (blk & (NSLOT - 1)) * 64;
      atomicAdd(&bnsum[s + tid], sbn[tid]);
      atomicAdd(&bnss[s + tid], sbn[8 + tid]);
    }
  }
  gsync(bar_arr, bar_go, 4, blk, tid);

  // ---- P5: compact levels 3+4 (block 0)  ||  conv0 8->16 + BN1 ----
  if (blk == 0) {
    cscan_phase<16, 1, 8, true>(0, tid, idx3, list3, cnt, 3, idx4, smem);
    __syncthreads();
    cscan_phase<8, 1, 1, false>(0, tid, idx4, list4, cnt, 4,
                                (unsigned short*)0, smem);
  } else {
    conv_loop<8, 16, 16, 64, 0>(blk - 1, NBLK - 1, blk, tid, h0, idx0, list1,
                                cnt, 0, 1, w0, bnsum, bnss, g0, b0,
                                bnsum + 1024, bnss + 1024, h1, smem);
  }
  gsync(bar_arr, bar_go, 5, blk, tid);

  // ---- P6: conv1 16->32 + BN2 ----
  conv_loop<16, 32, 32, 32, 0>(blk, NBLK, blk, tid, h1, idx1, list2, cnt, 1, 2,
                               w1, bnsum + 1024, bnss + 1024, g1, b1,
                               bnsum + 2048, bnss + 2048, h2, smem);
  gsync(bar_arr, bar_go, 6, blk, tid);

  // ---- P7: conv2 32->64 + BN3 ----
  conv_loop<32, 64, 16, 16, 0>(blk, NBLK, blk, tid, h2, idx2, list3, cnt, 2, 3,
                               w2, bnsum + 2048, bnss + 2048, g2, b2,
                               bnsum + 3072, bnss + 3072, h3, smem);
  gsync(bar_arr, bar_go, 7, blk, tid);

  // ---- P8: conv3 64->128 dense ----
  conv_loop<64, 128, 8, 8, 1>(blk, NBLK, blk, tid, h3, idx3, list4, cnt, 3, 4,
                              w3, bnsum + 3072, bnss + 3072, g3, b3, (float*)0,
                              (float*)0, h4, smem);
  gsync(bar_arr, bar_go, 8, blk, tid);

  // ---- P9: masked max-pool 8^3 -> 4^3 ----
  {
    int item = blk * NTHR + tid;
    if (item < NB * 128 * 64) {
      int sp = item & 63;
      int c = (item >> 6) & 127;
      int b = item >> 13;
      int Z = sp & 3, Y = (sp >> 2) & 3, X = sp >> 4;
      float m = NEGF;
      int any = 0;
#pragma unroll
      for (int t = 0; t < 8; t++) {
        int kd = t >> 2, kh = (t >> 1) & 1, kw = t & 1;
        int csp = ((2 * X + kd) * 8 + 2 * Y + kh) * 8 + 2 * Z + kw;
        if (idx4[b * 512 + csp] != EMPTYV) {
          any = 1;
          m = fmaxf(m, h4[((size_t)b * 128 + c) * 512 + csp]);
        }
      }
      h5[((size_t)b * 128 + c) * 64 + sp] = any ? m : 0.f;
      if (c == 0) mask5[b * 64 + sp] = any;
    }
  }
  gsync(bar_arr, bar_go, 9, blk, tid);

  // ---- P10: pool 4^3 -> 2^3 + ReLU + linear (block 0) ----
  if (blk == 0) {
    float* h6s = smem;  // 2048
#pragma unroll
    for (int j = 0; j < 8; j++) {
      int e = tid * 8 + j;  // e = b*1024 + c*8 + sp
      int sp = e & 7, c = (e >> 3) & 127, b = e >> 10;
      int Z = sp & 1, Y = (sp >> 1) & 1, X = sp >> 2;
      float m = NEGF;
      int any = 0;
#pragma unroll
      for (int t = 0; t < 8; t++) {
        int kd = t >> 2, kh = (t >> 1) & 1, kw = t & 1;
        int csp = ((2 * X + kd) * 4 + 2 * Y + kh) * 4 + 2 * Z + kw;
        if (mask5[b * 64 + csp]) {
          any = 1;
          m = fmaxf(m, h5[((size_t)b * 128 + c) * 64 + csp]);
        }
      }
      h6s[e] = any ? fmaxf(m, 0.f) : 0.f;
    }
    __syncthreads();
    int wave = tid >> 6, lane = tid & 63;
    int b = wave >> 1, o = wave & 1;
    float s = 0.f;
    for (int k = lane; k < 1024; k += 64)
      s += h6s[b * 1024 + k] * Wc[o * 1024 + k];
#pragma unroll
    for (int off = 32; off > 0; off >>= 1) s += __shfl_down(s, off, 64);
    if (lane == 0) out[240000 + b * 2 + o] = s + bcv[o];
  }
}

// ---------------- host ----------------
extern "C" void kernel_launch(void* const* d_in, const int* in_sizes, int n_in,
                              void* d_out, int out_size, void* d_ws,
                              size_t ws_size, hipStream_t stream) {
  const float* pc = (const float*)d_in[0];
  const float* wsub = (const float*)d_in[1];
  const float* w0 = (const float*)d_in[2];
  const float* w1 = (const float*)d_in[3];
  const float* w2 = (const float*)d_in[4];
  const float* w3 = (const float*)d_in[5];
  const float* g0 = (const float*)d_in[6];
  const float* g1 = (const float*)d_in[7];
  const float* g2 = (const float*)d_in[8];
  const float* g3 = (const float*)d_in[9];
  const float* b0 = (const float*)d_in[10];
  const float* b1 = (const float*)d_in[11];
  const float* b2 = (const float*)d_in[12];
  const float* b3 = (const float*)d_in[13];
  const float* Wc = (const float*)d_in[14];
  const float* bc = (const float*)d_in[15];
  float* out = (float*)d_out;
  char* base = (char*)d_ws;

  hipMemsetAsync(base + OFF_BAR, 0, 512, stream);  // barrier state
  // Guard: idx grids must start != MARKV (write-all scans fix them up).
  hipMemsetAsync(base + OFF_IDX0, 0xAA, OFF_LIST0 - OFF_IDX0, stream);

  k_all<<<dim3(NBLK), dim3(NTHR), 0, stream>>>(pc, wsub, w0, w1, w2, w3, g0, g1,
                                               g2, g3, b0, b1, b2, b3, Wc, bc,
                                               out, base);
}

// Round 11
// 523.110 us; speedup vs baseline: 4.5491x; 4.5491x over previous
//
#include <hip/hip_runtime.h>
#include <math.h>

// Whole sparse masked-3D-CNN pipeline in ONE persistent kernel (plain launch,
// 512 blocks x 256 thr; co-residency by occupancy arithmetic).
// Round-11 change: grid barrier rebuilt after round-10 profile showed the
// ACQUIRE-in-poll-loop emitted an L2-invalidate per poll (2.4M/barrier).
// Now: RELAXED polling (coherent-bypass loads, no cache ops), ONE
// __threadfence per block per barrier side (tid==0 only), arrivals/go flags
// spread over 64 separate cachelines, s_sleep backoff.

#define NPTS 60000
#define NB 2
#define NEGF -3.0e38f
#define EPSF 1.0e-4f
#define MARKV 0xFFFEu
#define EMPTYV 0xFFFFu
#define NSLOT 16
#define NBLK 512
#define NTHR 256

constexpr int NV0 = NB * 128 * 128 * 128;
constexpr int NV1 = NB * 64 * 64 * 64;
constexpr int NV2 = NB * 32 * 32 * 32;
constexpr int NV3 = NB * 16 * 16 * 16;
constexpr int NV4 = NB * 8 * 8 * 8;

// ---- workspace layout (bytes) ----
constexpr size_t OFF_CNT   = 0;       // int[16]
constexpr size_t OFF_BNSUM = 1024;    // float[4][NSLOT][64]
constexpr size_t OFF_BNSS  = 17408;   // float[4][NSLOT][64]
constexpr size_t OFF_MASK5 = 33792;   // int[128] -> ends 34304
constexpr size_t OFF_BAR   = 34816;   // 16KB: arr[64] + go[64], 128B stride (memset 0)
constexpr size_t OFF_FCOMP = 51200;   // float[NPTS] -> ends 291200
constexpr size_t OFF_IDX0  = 294912;                       // u16[NV0]
constexpr size_t OFF_IDX1  = OFF_IDX0 + (size_t)NV0 * 2;
constexpr size_t OFF_IDX2  = OFF_IDX1 + (size_t)NV1 * 2;
constexpr size_t OFF_IDX3  = OFF_IDX2 + (size_t)NV2 * 2;
constexpr size_t OFF_IDX4  = OFF_IDX3 + (size_t)NV3 * 2;
constexpr size_t OFF_LIST0 = OFF_IDX4 + (size_t)NV4 * 2;
constexpr size_t OFF_LIST1 = OFF_LIST0 + (size_t)NPTS * 4;
constexpr size_t OFF_LIST2 = OFF_LIST1 + (size_t)NPTS * 4;
constexpr size_t OFF_LIST3 = OFF_LIST2 + (size_t)NPTS * 4;
constexpr size_t OFF_LIST4 = OFF_LIST3 + (size_t)NV3 * 4;
constexpr size_t OFF_H0 = OFF_LIST4 + (size_t)NV4 * 4;     // NPTS*8
constexpr size_t OFF_H1 = OFF_H0 + (size_t)NPTS * 8 * 4;   // NPTS*16
constexpr size_t OFF_H2 = OFF_H1 + (size_t)NPTS * 16 * 4;  // NPTS*32
constexpr size_t OFF_H3 = OFF_H2 + (size_t)NPTS * 32 * 4;  // NV3*64
constexpr size_t OFF_H4 = OFF_H3 + (size_t)NV3 * 64 * 4;   // dense [b][128][8^3]
constexpr size_t OFF_H5 = OFF_H4 + (size_t)NV4 * 128 * 4;  // [b][128][4^3]

// ---- grid barrier v2: relaxed polling, one fence per block per side ----
// arr[i*32]: arrival counter for blocks with (blk&63)==i  (128B apart)
// go[i*32] : replicated release flag polled by blocks with (blk&63)==i
__device__ __forceinline__ void gsync(unsigned* bar_arr, unsigned* bar_go,
                                      unsigned gen, int blk, int tid) {
  __syncthreads();  // all waves' prior stores drained to L2 (compiler waitcnt)
  if (blk == 0) {
    if (tid < 64) {
      if (tid == 0) {
        __threadfence();  // release: writeback this XCD's L2, once per block
        __hip_atomic_fetch_add(&bar_arr[0], 1u, __ATOMIC_RELAXED,
                               __HIP_MEMORY_SCOPE_AGENT);
      }
      unsigned target = gen * (unsigned)NBLK;
      while (true) {
        unsigned v = __hip_atomic_load(&bar_arr[tid * 32], __ATOMIC_RELAXED,
                                       __HIP_MEMORY_SCOPE_AGENT);
        unsigned s = v;
#pragma unroll
        for (int off = 32; off; off >>= 1) s += __shfl_xor(s, off, 64);
        if (s >= target) break;
        __builtin_amdgcn_s_sleep(2);
      }
      if (tid == 0) __threadfence();  // acquire for block 0's later reads
      __hip_atomic_store(&bar_go[tid * 32], gen, __ATOMIC_RELAXED,
                         __HIP_MEMORY_SCOPE_AGENT);
    }
  } else if (tid == 0) {
    __threadfence();  // release: writeback this XCD's L2, once per block
    __hip_atomic_fetch_add(&bar_arr[(blk & 63) * 32], 1u, __ATOMIC_RELAXED,
                           __HIP_MEMORY_SCOPE_AGENT);
    while (__hip_atomic_load(&bar_go[(blk & 63) * 32], __ATOMIC_RELAXED,
                             __HIP_MEMORY_SCOPE_AGENT) < gen)
      __builtin_amdgcn_s_sleep(8);
    __threadfence();  // acquire: invalidate stale L1/L2, once per block
  }
  __syncthreads();
}

// ---- write-all block-scan compaction (marks -> contiguous ids) ----
template <int SL, int PBLK, int IT4, bool HASPAR>
__device__ __forceinline__ void cscan_phase(int blk, int tid,
                                            unsigned short* __restrict__ idx,
                                            int* __restrict__ list,
                                            int* __restrict__ cnt, int slot,
                                            unsigned short* __restrict__ idx_par,
                                            float* smem) {
  if (blk >= PBLK) return;
  int* sw = (int*)smem;  // [0..3]=wave totals/offsets, [4]=block base
  constexpr int NT = PBLK * NTHR;
  int t64 = blk * NTHR + tid;
  const ushort4* p4 = (const ushort4*)idx;
  int c = 0;
  ushort4 uu[IT4];
#pragma unroll
  for (int k = 0; k < IT4; k++) {
    uu[k] = p4[t64 + k * NT];
    c += (uu[k].x == MARKV) + (uu[k].y == MARKV) + (uu[k].z == MARKV) +
         (uu[k].w == MARKV);
  }
  int lane = tid & 63, wid = tid >> 6;
  int x = c;
#pragma unroll
  for (int off = 1; off < 64; off <<= 1) {
    int y = __shfl_up(x, off, 64);
    if (lane >= off) x += y;
  }
  if (lane == 63) sw[wid] = x;
  __syncthreads();
  if (tid == 0) {
    int r = 0;
#pragma unroll
    for (int wv = 0; wv < 4; wv++) { int t = sw[wv]; sw[wv] = r; r += t; }
    sw[4] = r ? atomicAdd(&cnt[slot], r) : 0;
  }
  __syncthreads();
  int my = sw[4] + sw[wid] + (x - c);
  ushort4* p4w = (ushort4*)idx;
#pragma unroll
  for (int k = 0; k < IT4; k++) {
    int i4 = t64 + k * NT;
    unsigned short in[4] = {uu[k].x, uu[k].y, uu[k].z, uu[k].w};
    unsigned short o[4];
#pragma unroll
    for (int j = 0; j < 4; j++) {
      if (in[j] == MARKV) {
        int v = i4 * 4 + j;
        o[j] = (unsigned short)my;
        list[my] = v;
        my++;
        if (HASPAR) {
          int z = v & (SL - 1), y = (v / SL) & (SL - 1),
              xx = (v / (SL * SL)) & (SL - 1), b = v / (SL * SL * SL);
          constexpr int SP = SL / 2;
          int pv = ((b * SP + (xx >> 1)) * SP + (y >> 1)) * SP + (z >> 1);
          idx_par[pv] = (unsigned short)MARKV;
        }
      } else {
        o[j] = (unsigned short)EMPTYV;
      }
    }
    p4w[i4] = make_ushort4(o[0], o[1], o[2], o[3]);
  }
}

// ---- stride-2 VALID 2^3 conv, grid-stride over (oc-group, parent-group) ----
template <int Ci, int Co, int OCCHUNK, int SLpar, int DENSE_OUT>
__device__ __forceinline__ void conv_loop(
    int first, int avail, int blk, int tid, const float* __restrict__ hin,
    const unsigned short* __restrict__ idxc, const int* __restrict__ listpar,
    const int* __restrict__ cnt, int slot_bn, int slot_par,
    const float* __restrict__ w, const float* __restrict__ bnsum_in,
    const float* __restrict__ bnss_in, const float* __restrict__ g,
    const float* __restrict__ beta, float* __restrict__ bnsum_out,
    float* __restrict__ bnss_out, float* __restrict__ hout, float* smem) {
  constexpr int TPP = OCCHUNK / 8;   // threads per parent
  constexpr int PPB = NTHR / TPP;    // parents per block
  constexpr int NOCG = Co / OCCHUNK;
  int n = cnt[slot_par];
  int npg = (n + PPB - 1) / PPB;
  int nitems = npg * NOCG;
  float* wl = smem;          // <= 4096 floats for all instantiations
  float* sl = smem + 4096;   // Ci <= 64
  float* bl = smem + 4160;
  float* bnl = smem + 4224;  // 2*OCCHUNK <= 64
  for (int item = first; item < nitems; item += avail) {
    int pg = item % npg;
    int ocbase = (item / npg) * OCCHUNK;
    __syncthreads();  // previous iteration's readers of wl are done
    for (int i = tid; i < Ci * 8 * OCCHUNK; i += NTHR) {
      int ol = i % OCCHUNK;
      int it = i / OCCHUNK;  // ci*8 + t
      int ci = it >> 3, t = it & 7;
      wl[i] = w[((size_t)(ocbase + ol) * Ci + ci) * 8 + t];
    }
    if (tid < Ci) {
      float nn = (float)cnt[slot_bn];
      float s = 0.f, ss = 0.f;
#pragma unroll
      for (int k = 0; k < NSLOT; k++) {
        s += bnsum_in[k * 64 + tid];
        ss += bnss_in[k * 64 + tid];
      }
      float mu = s / nn;
      float var = fmaxf(ss / nn - mu * mu, 0.f);
      float sc = g[tid] / sqrtf(var + EPSF);
      sl[tid] = sc;
      bl[tid] = beta[tid] - mu * sc;
    }
    if (!DENSE_OUT && tid < 2 * OCCHUNK) bnl[tid] = 0.f;
    __syncthreads();
    int pid = pg * PPB + tid / TPP;
    int og = tid % TPP;
    bool act = pid < n;
    float acc[8] = {0, 0, 0, 0, 0, 0, 0, 0};
    int Xc = 0, Yc = 0, Zc = 0, bb = 0;
    if (act) {
      int pv = listpar[pid];
      constexpr int SL = SLpar, SC = SLpar * 2;
      Zc = pv & (SL - 1);
      Yc = (pv / SL) & (SL - 1);
      Xc = (pv / (SL * SL)) & (SL - 1);
      bb = pv / (SL * SL * SL);
      for (int t = 0; t < 8; t++) {
        int kd = t >> 2, kh = (t >> 1) & 1, kw = t & 1;
        int cv = ((bb * SC + 2 * Xc + kd) * SC + 2 * Yc + kh) * SC + 2 * Zc + kw;
        unsigned e = idxc[cv];
        if (e >= 0xFFFEu) continue;  // empty child contributes 0
        const float* hp = hin + (size_t)e * Ci;
#pragma unroll
        for (int i = 0; i < Ci; i += 4) {
          float4 xv = *(const float4*)(hp + i);
          float y0 = fmaxf(fmaf(xv.x, sl[i + 0], bl[i + 0]), 0.f);
          float y1 = fmaxf(fmaf(xv.y, sl[i + 1], bl[i + 1]), 0.f);
          float y2 = fmaxf(fmaf(xv.z, sl[i + 2], bl[i + 2]), 0.f);
          float y3 = fmaxf(fmaf(xv.w, sl[i + 3], bl[i + 3]), 0.f);
          const float* wp0 = &wl[((i + 0) * 8 + t) * OCCHUNK + og * 8];
          const float* wp1 = &wl[((i + 1) * 8 + t) * OCCHUNK + og * 8];
          const float* wp2 = &wl[((i + 2) * 8 + t) * OCCHUNK + og * 8];
          const float* wp3 = &wl[((i + 3) * 8 + t) * OCCHUNK + og * 8];
#pragma unroll
          for (int o = 0; o < 8; o++) {
            acc[o] = fmaf(y0, wp0[o], acc[o]);
            acc[o] = fmaf(y1, wp1[o], acc[o]);
            acc[o] = fmaf(y2, wp2[o], acc[o]);
            acc[o] = fmaf(y3, wp3[o], acc[o]);
          }
        }
      }
      if (!DENSE_OUT) {
        float* op = hout + (size_t)pid * Co + ocbase + og * 8;
#pragma unroll
        for (int o = 0; o < 8; o++) op[o] = acc[o];
      } else {
        int sp = (Xc * 8 + Yc) * 8 + Zc;  // SLpar == 8
#pragma unroll
        for (int o = 0; o < 8; o++)
          hout[((size_t)bb * 128 + ocbase + og * 8 + o) * 512 + sp] = acc[o];
      }
    }
    if (!DENSE_OUT) {
      int lane = tid & 63;
#pragma unroll
      for (int o = 0; o < 8; o++) {
        float a = acc[o], q = a * a;
#pragma unroll
        for (int off = TPP; off < 64; off <<= 1) {
          a += __shfl_down(a, off, 64);
          q += __shfl_down(q, off, 64);
        }
        if (lane < TPP) {  // og == lane here
          atomicAdd(&bnl[lane * 8 + o], a);
          atomicAdd(&bnl[OCCHUNK + lane * 8 + o], q);
        }
      }
      __syncthreads();
      if (tid < OCCHUNK) {
        int s = (blk & (NSLOT - 1)) * 64;
        atomicAdd(&bnsum_out[s + ocbase + tid], bnl[tid]);
        atomicAdd(&bnss_out[s + ocbase + tid], bnl[OCCHUNK + tid]);
      }
    }
  }
}

// ---------------- the mega-kernel ----------------
__global__ __launch_bounds__(NTHR, 4) void k_all(
    const float* __restrict__ pc, const float* __restrict__ wsub,
    const float* __restrict__ w0, const float* __restrict__ w1,
    const float* __restrict__ w2, const float* __restrict__ w3,
    const float* __restrict__ g0, const float* __restrict__ g1,
    const float* __restrict__ g2, const float* __restrict__ g3,
    const float* __restrict__ b0, const float* __restrict__ b1,
    const float* __restrict__ b2, const float* __restrict__ b3,
    const float* __restrict__ Wc, const float* __restrict__ bcv,
    float* __restrict__ out, char* __restrict__ base) {
  __shared__ float smem[4352];  // 17408 B
  int blk = blockIdx.x, tid = threadIdx.x;

  int* cnt = (int*)(base + OFF_CNT);
  float* bnsum = (float*)(base + OFF_BNSUM);
  float* bnss = (float*)(base + OFF_BNSS);
  int* mask5 = (int*)(base + OFF_MASK5);
  unsigned* bar_arr = (unsigned*)(base + OFF_BAR);
  unsigned* bar_go = (unsigned*)(base + OFF_BAR + 8192);
  float* fcomp = (float*)(base + OFF_FCOMP);
  unsigned short* idx0 = (unsigned short*)(base + OFF_IDX0);
  unsigned short* idx1 = (unsigned short*)(base + OFF_IDX1);
  unsigned short* idx2 = (unsigned short*)(base + OFF_IDX2);
  unsigned short* idx3 = (unsigned short*)(base + OFF_IDX3);
  unsigned short* idx4 = (unsigned short*)(base + OFF_IDX4);
  int* list0 = (int*)(base + OFF_LIST0);
  int* list1 = (int*)(base + OFF_LIST1);
  int* list2 = (int*)(base + OFF_LIST2);
  int* list3 = (int*)(base + OFF_LIST3);
  int* list4 = (int*)(base + OFF_LIST4);
  float* h0 = (float*)(base + OFF_H0);
  float* h1 = (float*)(base + OFF_H1);
  float* h2 = (float*)(base + OFF_H2);
  float* h3 = (float*)(base + OFF_H3);
  float* h4 = (float*)(base + OFF_H4);
  float* h5 = (float*)(base + OFF_H5);

  // ---- P1: clear cnt/bn/fcomp, mark idx0, write coords ----
  {
    int gid = blk * NTHR + tid;  // 131072 threads
    if (gid < 2112) ((int4*)base)[gid] = make_int4(0, 0, 0, 0);
    if (gid < 15000) ((float4*)fcomp)[gid] = make_float4(0.f, 0.f, 0.f, 0.f);
    if (gid < NPTS) {
      const float* p = pc + (size_t)gid * 5;
      float fb = p[0], fx = p[1], fy = p[2], fz = p[3];
      ((float4*)out)[gid] = make_float4(fb, fx, fy, fz);
      int b = (int)fb, xx = (int)fx, yy = (int)fy, zz = (int)fz;
      int v = ((b * 128 + xx) * 128 + yy) * 128 + zz;
      idx0[v] = (unsigned short)MARKV;
    }
  }
  gsync(bar_arr, bar_go, 1, blk, tid);

  // ---- P2: compact level 0 (write-all; marks idx1 parents) ----
  cscan_phase<128, 512, 8, true>(blk, tid, idx0, list0, cnt, 0, idx1, smem);
  gsync(bar_arr, bar_go, 2, blk, tid);

  // ---- P3: compact level 1 (blocks 0..63)  ||  point-feature scatter ----
  if (blk < 64) {
    cscan_phase<64, 64, 8, true>(blk, tid, idx1, list1, cnt, 1, idx2, smem);
  } else {
    int i = (blk - 64) * NTHR + tid;
    if (i < NPTS) {
      const float* p = pc + (size_t)i * 5;
      int b = (int)p[0], xx = (int)p[1], yy = (int)p[2], zz = (int)p[3];
      float f = p[4];
      int v = ((b * 128 + xx) * 128 + yy) * 128 + zz;
      unsigned e = idx0[v];
      atomicAdd(&fcomp[e], f);
    }
  }
  gsync(bar_arr, bar_go, 3, blk, tid);

  // ---- P4: compact level 2 (blocks 0..15)  ||  submanifold conv + BN0 ----
  if (blk < 16) {
    cscan_phase<32, 16, 4, true>(blk, tid, idx2, list2, cnt, 2, idx3, smem);
  } else {
    float* wl = smem;         // 216
    float* sbn = smem + 216;  // 16
    for (int i = tid; i < 216; i += NTHR) wl[i] = wsub[i];
    if (tid < 16) sbn[tid] = 0.f;
    __syncthreads();
    int n0 = cnt[0];
    int ngrp = (n0 + 63) >> 6;  // 64 points per group (4 threads/point)
    int sub = tid & 3;
    int lane = tid & 63;
    for (int grp = blk - 16; grp < ngrp; grp += (NBLK - 16)) {
      int pid = grp * 64 + (tid >> 2);
      bool act = pid < n0;
      float acc[8] = {0, 0, 0, 0, 0, 0, 0, 0};
      if (act) {
        int v = list0[pid];
        int z = v & 127, y = (v >> 7) & 127, x = (v >> 14) & 127, b = v >> 21;
        int t0 = sub * 7, t1 = t0 + 7 > 27 ? 27 : t0 + 7;
        for (int t = t0; t < t1; t++) {
          int kd = t / 9, kh = (t / 3) % 3, kw = t % 3;
          int xx = x + kd - 1, yy = y + kh - 1, zz = z + kw - 1;
          if ((unsigned)xx < 128u && (unsigned)yy < 128u &&
              (unsigned)zz < 128u) {
            unsigned e = idx0[((b * 128 + xx) * 128 + yy) * 128 + zz];
            if (e != EMPTYV) {
              float val = fcomp[e];
#pragma unroll
              for (int o = 0; o < 8; o++)
                acc[o] = fmaf(val, wl[o * 27 + t], acc[o]);
            }
          }
        }
      }
#pragma unroll
      for (int o = 0; o < 8; o++) {  // combine the 4 tap-groups
        acc[o] += __shfl_xor(acc[o], 1, 64);
        acc[o] += __shfl_xor(acc[o], 2, 64);
      }
      if (act)
        ((float2*)(h0 + (size_t)pid * 8))[sub] =
            make_float2(acc[sub * 2], acc[sub * 2 + 1]);
#pragma unroll
      for (int o = 0; o < 8; o++) {  // each point counted once per channel
        float a = ((o >> 1) == sub && act) ? acc[o] : 0.f;
        float q = a * a;
#pragma unroll
        for (int off = 32; off > 0; off >>= 1) {
          a += __shfl_down(a, off, 64);
          q += __shfl_down(q, off, 64);
        }
        if (lane == 0) {
          atomicAdd(&sbn[o], a);
          atomicAdd(&sbn[8 + o], q);
        }
      }
    }
    __syncthreads();
    if (tid < 8) {
      int s = (blk & (NSLOT - 1)) * 64;
      atomicAdd(&bnsum[s + tid], sbn[tid]);
      atomicAdd(&bnss[s + tid], sbn[8 + tid]);
    }
  }
  gsync(bar_arr, bar_go, 4, blk, tid);

  // ---- P5: compact levels 3+4 (block 0)  ||  conv0 8->16 + BN1 ----
  if (blk == 0) {
    cscan_phase<16, 1, 8, true>(0, tid, idx3, list3, cnt, 3, idx4, smem);
    __syncthreads();
    cscan_phase<8, 1, 1, false>(0, tid, idx4, list4, cnt, 4,
                                (unsigned short*)0, smem);
  } else {
    conv_loop<8, 16, 16, 64, 0>(blk - 1, NBLK - 1, blk, tid, h0, idx0, list1,
                                cnt, 0, 1, w0, bnsum, bnss, g0, b0,
                                bnsum + 1024, bnss + 1024, h1, smem);
  }
  gsync(bar_arr, bar_go, 5, blk, tid);

  // ---- P6: conv1 16->32 + BN2 ----
  conv_loop<16, 32, 32, 32, 0>(blk, NBLK, blk, tid, h1, idx1, list2, cnt, 1, 2,
                               w1, bnsum + 1024, bnss + 1024, g1, b1,
                               bnsum + 2048, bnss + 2048, h2, smem);
  gsync(bar_arr, bar_go, 6, blk, tid);

  // ---- P7: conv2 32->64 + BN3 ----
  conv_loop<32, 64, 16, 16, 0>(blk, NBLK, blk, tid, h2, idx2, list3, cnt, 2, 3,
                               w2, bnsum + 2048, bnss + 2048, g2, b2,
                               bnsum + 3072, bnss + 3072, h3, smem);
  gsync(bar_arr, bar_go, 7, blk, tid);

  // ---- P8: conv3 64->128 dense ----
  conv_loop<64, 128, 8, 8, 1>(blk, NBLK, blk, tid, h3, idx3, list4, cnt, 3, 4,
                              w3, bnsum + 3072, bnss + 3072, g3, b3, (float*)0,
                              (float*)0, h4, smem);
  gsync(bar_arr, bar_go, 8, blk, tid);

  // ---- P9: masked max-pool 8^3 -> 4^3 ----
  {
    int item = blk * NTHR + tid;
    if (item < NB * 128 * 64) {
      int sp = item & 63;
      int c = (item >> 6) & 127;
      int b = item >> 13;
      int Z = sp & 3, Y = (sp >> 2) & 3, X = sp >> 4;
      float m = NEGF;
      int any = 0;
#pragma unroll
      for (int t = 0; t < 8; t++) {
        int kd = t >> 2, kh = (t >> 1) & 1, kw = t & 1;
        int csp = ((2 * X + kd) * 8 + 2 * Y + kh) * 8 + 2 * Z + kw;
        if (idx4[b * 512 + csp] != EMPTYV) {
          any = 1;
          m = fmaxf(m, h4[((size_t)b * 128 + c) * 512 + csp]);
        }
      }
      h5[((size_t)b * 128 + c) * 64 + sp] = any ? m : 0.f;
      if (c == 0) mask5[b * 64 + sp] = any;
    }
  }
  gsync(bar_arr, bar_go, 9, blk, tid);

  // ---- P10: pool 4^3 -> 2^3 + ReLU + linear (block 0) ----
  if (blk == 0) {
    float* h6s = smem;  // 2048
#pragma unroll
    for (int j = 0; j < 8; j++) {
      int e = tid * 8 + j;  // e = b*1024 + c*8 + sp
      int sp = e & 7, c = (e >> 3) & 127, b = e >> 10;
      int Z = sp & 1, Y = (sp >> 1) & 1, X = sp >> 2;
      float m = NEGF;
      int any = 0;
#pragma unroll
      for (int t = 0; t < 8; t++) {
        int kd = t >> 2, kh = (t >> 1) & 1, kw = t & 1;
        int csp = ((2 * X + kd) * 4 + 2 * Y + kh) * 4 + 2 * Z + kw;
        if (mask5[b * 64 + csp]) {
          any = 1;
          m = fmaxf(m, h5[((size_t)b * 128 + c) * 64 + csp]);
        }
      }
      h6s[e] = any ? fmaxf(m, 0.f) : 0.f;
    }
    __syncthreads();
    int wave = tid >> 6, lane = tid & 63;
    int b = wave >> 1, o = wave & 1;
    float s = 0.f;
    for (int k = lane; k < 1024; k += 64)
      s += h6s[b * 1024 + k] * Wc[o * 1024 + k];
#pragma unroll
    for (int off = 32; off > 0; off >>= 1) s += __shfl_down(s, off, 64);
    if (lane == 0) out[240000 + b * 2 + o] = s + bcv[o];
  }
}

// ---------------- host ----------------
extern "C" void kernel_launch(void* const* d_in, const int* in_sizes, int n_in,
                              void* d_out, int out_size, void* d_ws,
                              size_t ws_size, hipStream_t stream) {
  const float* pc = (const float*)d_in[0];
  const float* wsub = (const float*)d_in[1];
  const float* w0 = (const float*)d_in[2];
  const float* w1 = (const float*)d_in[3];
  const float* w2 = (const float*)d_in[4];
  const float* w3 = (const float*)d_in[5];
  const float* g0 = (const float*)d_in[6];
  const float* g1 = (const float*)d_in[7];
  const float* g2 = (const float*)d_in[8];
  const float* g3 = (const float*)d_in[9];
  const float* b0 = (const float*)d_in[10];
  const float* b1 = (const float*)d_in[11];
  const float* b2 = (const float*)d_in[12];
  const float* b3 = (const float*)d_in[13];
  const float* Wc = (const float*)d_in[14];
  const float* bc = (const float*)d_in[15];
  float* out = (float*)d_out;
  char* base = (char*)d_ws;

  hipMemsetAsync(base + OFF_BAR, 0, 16384, stream);  // barrier state
  // Guard: idx grids must start != MARKV (write-all scans fix them up).
  hipMemsetAsync(base + OFF_IDX0, 0xAA, OFF_LIST0 - OFF_IDX0, stream);

  k_all<<<dim3(NBLK), dim3(NTHR), 0, stream>>>(pc, wsub, w0, w1, w2, w3, g0, g1,
                                               g2, g3, b0, b1, b2, b3, Wc, bc,
                                               out, base);
}

// Round 12
// 389.574 us; speedup vs baseline: 6.1085x; 1.3428x over previous
//
#include <hip/hip_runtime.h>
#include <math.h>

// Whole sparse masked-3D-CNN pipeline in ONE persistent kernel.
// Round-12 change: barrier v3. Round-11 profile showed ~40us/barrier from
// 1024 agent-scope __threadfence() calls (each = whole-L2 wbl2+inv) wiping
// L2 64x per XCD per barrier. v3 dedupes to ONE flush + ONE invalidate per
// XCD per barrier via CAS-claimed leaders (XCC_ID from s_getreg, m09),
// 2-round release (goA: all arrived -> 8 flush winners -> goB: all flushed
// -> 8 inv winners -> xcd_go). All polling is RELAXED fabric atomics.

#define NPTS 60000
#define NB 2
#define NEGF -3.0e38f
#define EPSF 1.0e-4f
#define MARKV 0xFFFEu
#define EMPTYV 0xFFFFu
#define NSLOT 16
#define NBLK 512
#define NTHR 256

constexpr int NV0 = NB * 128 * 128 * 128;
constexpr int NV1 = NB * 64 * 64 * 64;
constexpr int NV2 = NB * 32 * 32 * 32;
constexpr int NV3 = NB * 16 * 16 * 16;
constexpr int NV4 = NB * 8 * 8 * 8;

// ---- workspace layout (bytes) ----
constexpr size_t OFF_CNT   = 0;       // int[16]
constexpr size_t OFF_BNSUM = 1024;    // float[4][NSLOT][64]
constexpr size_t OFF_BNSS  = 17408;   // float[4][NSLOT][64]
constexpr size_t OFF_MASK5 = 33792;   // int[128] (fully rewritten by P9)
constexpr size_t OFF_BAR   = 34816;   // 28672 B barrier state (memset 0)
constexpr size_t OFF_FCOMP = 65536;   // float[NPTS]
constexpr size_t OFF_IDX0  = 327680;                       // u16[NV0]
constexpr size_t OFF_IDX1  = OFF_IDX0 + (size_t)NV0 * 2;
constexpr size_t OFF_IDX2  = OFF_IDX1 + (size_t)NV1 * 2;
constexpr size_t OFF_IDX3  = OFF_IDX2 + (size_t)NV2 * 2;
constexpr size_t OFF_IDX4  = OFF_IDX3 + (size_t)NV3 * 2;
constexpr size_t OFF_LIST0 = OFF_IDX4 + (size_t)NV4 * 2;
constexpr size_t OFF_LIST1 = OFF_LIST0 + (size_t)NPTS * 4;
constexpr size_t OFF_LIST2 = OFF_LIST1 + (size_t)NPTS * 4;
constexpr size_t OFF_LIST3 = OFF_LIST2 + (size_t)NPTS * 4;
constexpr size_t OFF_LIST4 = OFF_LIST3 + (size_t)NV3 * 4;
constexpr size_t OFF_H0 = OFF_LIST4 + (size_t)NV4 * 4;     // NPTS*8
constexpr size_t OFF_H1 = OFF_H0 + (size_t)NPTS * 8 * 4;   // NPTS*16
constexpr size_t OFF_H2 = OFF_H1 + (size_t)NPTS * 16 * 4;  // NPTS*32
constexpr size_t OFF_H3 = OFF_H2 + (size_t)NPTS * 32 * 4;  // NV3*64
constexpr size_t OFF_H4 = OFF_H3 + (size_t)NV3 * 64 * 4;   // dense [b][128][8^3]
constexpr size_t OFF_H5 = OFF_H4 + (size_t)NV4 * 128 * 4;  // [b][128][4^3]

// ---- barrier state sub-layout (within OFF_BAR, all 128B-strided lines) ----
// arr[64] @0, goA[64] @8192, goB[64] @16384, fcl[8] @24576, icl[8] @25600,
// xgo[8] @26624, gfl[1] @27648.   Total 27776 -> memset 28672.

__device__ __forceinline__ unsigned get_xcc() {
  unsigned x;
  asm volatile("s_getreg_b32 %0, hwreg(HW_REG_XCC_ID)" : "=s"(x));
  return x & 7u;
}
__device__ __forceinline__ unsigned aload(unsigned* p) {
  return __hip_atomic_load(p, __ATOMIC_RELAXED, __HIP_MEMORY_SCOPE_AGENT);
}
__device__ __forceinline__ void astore(unsigned* p, unsigned v) {
  __hip_atomic_store(p, v, __ATOMIC_RELAXED, __HIP_MEMORY_SCOPE_AGENT);
}
__device__ __forceinline__ void aadd(unsigned* p, unsigned v) {
  __hip_atomic_fetch_add(p, v, __ATOMIC_RELAXED, __HIP_MEMORY_SCOPE_AGENT);
}
__device__ __forceinline__ bool aclaim(unsigned* p, unsigned gen) {
  unsigned exp = gen - 1;
  return __hip_atomic_compare_exchange_strong(p, &exp, gen, __ATOMIC_RELAXED,
                                              __ATOMIC_RELAXED,
                                              __HIP_MEMORY_SCOPE_AGENT);
}

// ---- grid barrier v3: one L2-flush + one L2-inv per XCD per barrier ----
__device__ __forceinline__ void gsync(char* barb, unsigned gen, int blk,
                                      int tid) {
  unsigned* arr = (unsigned*)(barb);
  unsigned* goA = (unsigned*)(barb + 8192);
  unsigned* goB = (unsigned*)(barb + 16384);
  unsigned* fcl = (unsigned*)(barb + 24576);
  unsigned* icl = (unsigned*)(barb + 25600);
  unsigned* xgo = (unsigned*)(barb + 26624);
  unsigned* gfl = (unsigned*)(barb + 27648);
  __syncthreads();  // all waves' prior stores drained into this XCD's L2
  if (blk == 0) {
    if (tid < 64) {
      unsigned xcc = get_xcc();
      if (tid == 0) aadd(&arr[0], 1u);
      unsigned target = gen * (unsigned)NBLK;
      while (true) {  // master: sum 64 spread arrival counters
        unsigned s = aload(&arr[tid * 32]);
#pragma unroll
        for (int off = 32; off; off >>= 1) s += __shfl_xor(s, off, 64);
        if (s >= target) break;
        __builtin_amdgcn_s_sleep(2);
      }
      astore(&goA[tid * 32], gen);  // release round A
      if (tid == 0) {
        if (aclaim(&fcl[xcc * 32], gen)) {  // flush leader for this XCD
          __threadfence();                  // wbl2: publish XCD's L2 to L3
          aadd(gfl, 1u);
        }
      }
      while (aload(gfl) < 8u * gen) __builtin_amdgcn_s_sleep(2);
      astore(&goB[tid * 32], gen);  // release round B
      if (tid == 0) {
        if (aclaim(&icl[xcc * 32], gen)) {  // inv leader for this XCD
          __threadfence();                  // inv: drop stale local L2 lines
          astore(&xgo[xcc * 32], gen);
        } else {
          while (aload(&xgo[xcc * 32]) < gen) __builtin_amdgcn_s_sleep(2);
        }
      }
    }
  } else if (tid == 0) {
    unsigned xcc = get_xcc();
    aadd(&arr[(blk & 63) * 32], 1u);
    while (aload(&goA[(blk & 63) * 32]) < gen) __builtin_amdgcn_s_sleep(4);
    if (aclaim(&fcl[xcc * 32], gen)) {
      __threadfence();
      aadd(gfl, 1u);
    }
    while (aload(&goB[(blk & 63) * 32]) < gen) __builtin_amdgcn_s_sleep(4);
    if (aclaim(&icl[xcc * 32], gen)) {
      __threadfence();
      astore(&xgo[xcc * 32], gen);
    } else {
      while (aload(&xgo[xcc * 32]) < gen) __builtin_amdgcn_s_sleep(4);
    }
  }
  __syncthreads();
}

// ---- write-all block-scan compaction (marks -> contiguous ids) ----
template <int SL, int PBLK, int IT4, bool HASPAR>
__device__ __forceinline__ void cscan_phase(int blk, int tid,
                                            unsigned short* __restrict__ idx,
                                            int* __restrict__ list,
                                            int* __restrict__ cnt, int slot,
                                            unsigned short* __restrict__ idx_par,
                                            float* smem) {
  if (blk >= PBLK) return;
  int* sw = (int*)smem;  // [0..3]=wave totals/offsets, [4]=block base
  constexpr int NT = PBLK * NTHR;
  int t64 = blk * NTHR + tid;
  const ushort4* p4 = (const ushort4*)idx;
  int c = 0;
  ushort4 uu[IT4];
#pragma unroll
  for (int k = 0; k < IT4; k++) {
    uu[k] = p4[t64 + k * NT];
    c += (uu[k].x == MARKV) + (uu[k].y == MARKV) + (uu[k].z == MARKV) +
         (uu[k].w == MARKV);
  }
  int lane = tid & 63, wid = tid >> 6;
  int x = c;
#pragma unroll
  for (int off = 1; off < 64; off <<= 1) {
    int y = __shfl_up(x, off, 64);
    if (lane >= off) x += y;
  }
  if (lane == 63) sw[wid] = x;
  __syncthreads();
  if (tid == 0) {
    int r = 0;
#pragma unroll
    for (int wv = 0; wv < 4; wv++) { int t = sw[wv]; sw[wv] = r; r += t; }
    sw[4] = r ? atomicAdd(&cnt[slot], r) : 0;
  }
  __syncthreads();
  int my = sw[4] + sw[wid] + (x - c);
  ushort4* p4w = (ushort4*)idx;
#pragma unroll
  for (int k = 0; k < IT4; k++) {
    int i4 = t64 + k * NT;
    unsigned short in[4] = {uu[k].x, uu[k].y, uu[k].z, uu[k].w};
    unsigned short o[4];
#pragma unroll
    for (int j = 0; j < 4; j++) {
      if (in[j] == MARKV) {
        int v = i4 * 4 + j;
        o[j] = (unsigned short)my;
        list[my] = v;
        my++;
        if (HASPAR) {
          int z = v & (SL - 1), y = (v / SL) & (SL - 1),
              xx = (v / (SL * SL)) & (SL - 1), b = v / (SL * SL * SL);
          constexpr int SP = SL / 2;
          int pv = ((b * SP + (xx >> 1)) * SP + (y >> 1)) * SP + (z >> 1);
          idx_par[pv] = (unsigned short)MARKV;
        }
      } else {
        o[j] = (unsigned short)EMPTYV;
      }
    }
    p4w[i4] = make_ushort4(o[0], o[1], o[2], o[3]);
  }
}

// ---- stride-2 VALID 2^3 conv, grid-stride over (oc-group, parent-group) ----
template <int Ci, int Co, int OCCHUNK, int SLpar, int DENSE_OUT>
__device__ __forceinline__ void conv_loop(
    int first, int avail, int blk, int tid, const float* __restrict__ hin,
    const unsigned short* __restrict__ idxc, const int* __restrict__ listpar,
    const int* __restrict__ cnt, int slot_bn, int slot_par,
    const float* __restrict__ w, const float* __restrict__ bnsum_in,
    const float* __restrict__ bnss_in, const float* __restrict__ g,
    const float* __restrict__ beta, float* __restrict__ bnsum_out,
    float* __restrict__ bnss_out, float* __restrict__ hout, float* smem) {
  constexpr int TPP = OCCHUNK / 8;   // threads per parent
  constexpr int PPB = NTHR / TPP;    // parents per block
  constexpr int NOCG = Co / OCCHUNK;
  int n = cnt[slot_par];
  int npg = (n + PPB - 1) / PPB;
  int nitems = npg * NOCG;
  float* wl = smem;          // <= 4096 floats for all instantiations
  float* sl = smem + 4096;   // Ci <= 64
  float* bl = smem + 4160;
  float* bnl = smem + 4224;  // 2*OCCHUNK <= 64
  for (int item = first; item < nitems; item += avail) {
    int pg = item % npg;
    int ocbase = (item / npg) * OCCHUNK;
    __syncthreads();  // previous iteration's readers of wl are done
    for (int i = tid; i < Ci * 8 * OCCHUNK; i += NTHR) {
      int ol = i % OCCHUNK;
      int it = i / OCCHUNK;  // ci*8 + t
      int ci = it >> 3, t = it & 7;
      wl[i] = w[((size_t)(ocbase + ol) * Ci + ci) * 8 + t];
    }
    if (tid < Ci) {
      float nn = (float)cnt[slot_bn];
      float s = 0.f, ss = 0.f;
#pragma unroll
      for (int k = 0; k < NSLOT; k++) {
        s += bnsum_in[k * 64 + tid];
        ss += bnss_in[k * 64 + tid];
      }
      float mu = s / nn;
      float var = fmaxf(ss / nn - mu * mu, 0.f);
      float sc = g[tid] / sqrtf(var + EPSF);
      sl[tid] = sc;
      bl[tid] = beta[tid] - mu * sc;
    }
    if (!DENSE_OUT && tid < 2 * OCCHUNK) bnl[tid] = 0.f;
    __syncthreads();
    int pid = pg * PPB + tid / TPP;
    int og = tid % TPP;
    bool act = pid < n;
    float acc[8] = {0, 0, 0, 0, 0, 0, 0, 0};
    int Xc = 0, Yc = 0, Zc = 0, bb = 0;
    if (act) {
      int pv = listpar[pid];
      constexpr int SL = SLpar, SC = SLpar * 2;
      Zc = pv & (SL - 1);
      Yc = (pv / SL) & (SL - 1);
      Xc = (pv / (SL * SL)) & (SL - 1);
      bb = pv / (SL * SL * SL);
      for (int t = 0; t < 8; t++) {
        int kd = t >> 2, kh = (t >> 1) & 1, kw = t & 1;
        int cv = ((bb * SC + 2 * Xc + kd) * SC + 2 * Yc + kh) * SC + 2 * Zc + kw;
        unsigned e = idxc[cv];
        if (e >= 0xFFFEu) continue;  // empty child contributes 0
        const float* hp = hin + (size_t)e * Ci;
#pragma unroll
        for (int i = 0; i < Ci; i += 4) {
          float4 xv = *(const float4*)(hp + i);
          float y0 = fmaxf(fmaf(xv.x, sl[i + 0], bl[i + 0]), 0.f);
          float y1 = fmaxf(fmaf(xv.y, sl[i + 1], bl[i + 1]), 0.f);
          float y2 = fmaxf(fmaf(xv.z, sl[i + 2], bl[i + 2]), 0.f);
          float y3 = fmaxf(fmaf(xv.w, sl[i + 3], bl[i + 3]), 0.f);
          const float* wp0 = &wl[((i + 0) * 8 + t) * OCCHUNK + og * 8];
          const float* wp1 = &wl[((i + 1) * 8 + t) * OCCHUNK + og * 8];
          const float* wp2 = &wl[((i + 2) * 8 + t) * OCCHUNK + og * 8];
          const float* wp3 = &wl[((i + 3) * 8 + t) * OCCHUNK + og * 8];
#pragma unroll
          for (int o = 0; o < 8; o++) {
            acc[o] = fmaf(y0, wp0[o], acc[o]);
            acc[o] = fmaf(y1, wp1[o], acc[o]);
            acc[o] = fmaf(y2, wp2[o], acc[o]);
            acc[o] = fmaf(y3, wp3[o], acc[o]);
          }
        }
      }
      if (!DENSE_OUT) {
        float* op = hout + (size_t)pid * Co + ocbase + og * 8;
#pragma unroll
        for (int o = 0; o < 8; o++) op[o] = acc[o];
      } else {
        int sp = (Xc * 8 + Yc) * 8 + Zc;  // SLpar == 8
#pragma unroll
        for (int o = 0; o < 8; o++)
          hout[((size_t)bb * 128 + ocbase + og * 8 + o) * 512 + sp] = acc[o];
      }
    }
    if (!DENSE_OUT) {
      int lane = tid & 63;
#pragma unroll
      for (int o = 0; o < 8; o++) {
        float a = acc[o], q = a * a;
#pragma unroll
        for (int off = TPP; off < 64; off <<= 1) {
          a += __shfl_down(a, off, 64);
          q += __shfl_down(q, off, 64);
        }
        if (lane < TPP) {  // og == lane here
          atomicAdd(&bnl[lane * 8 + o], a);
          atomicAdd(&bnl[OCCHUNK + lane * 8 + o], q);
        }
      }
      __syncthreads();
      if (tid < OCCHUNK) {
        int s = (blk & (NSLOT - 1)) * 64;
        atomicAdd(&bnsum_out[s + ocbase + tid], bnl[tid]);
        atomicAdd(&bnss_out[s + ocbase + tid], bnl[OCCHUNK + tid]);
      }
    }
  }
}

// ---------------- the mega-kernel ----------------
__global__ __launch_bounds__(NTHR, 4) void k_all(
    const float* __restrict__ pc, const float* __restrict__ wsub,
    const float* __restrict__ w0, const float* __restrict__ w1,
    const float* __restrict__ w2, const float* __restrict__ w3,
    const float* __restrict__ g0, const float* __restrict__ g1,
    const float* __restrict__ g2, const float* __restrict__ g3,
    const float* __restrict__ b0, const float* __restrict__ b1,
    const float* __restrict__ b2, const float* __restrict__ b3,
    const float* __restrict__ Wc, const float* __restrict__ bcv,
    float* __restrict__ out, char* __restrict__ base) {
  __shared__ float smem[4352];  // 17408 B
  int blk = blockIdx.x, tid = threadIdx.x;

  int* cnt = (int*)(base + OFF_CNT);
  float* bnsum = (float*)(base + OFF_BNSUM);
  float* bnss = (float*)(base + OFF_BNSS);
  int* mask5 = (int*)(base + OFF_MASK5);
  char* barb = base + OFF_BAR;
  float* fcomp = (float*)(base + OFF_FCOMP);
  unsigned short* idx0 = (unsigned short*)(base + OFF_IDX0);
  unsigned short* idx1 = (unsigned short*)(base + OFF_IDX1);
  unsigned short* idx2 = (unsigned short*)(base + OFF_IDX2);
  unsigned short* idx3 = (unsigned short*)(base + OFF_IDX3);
  unsigned short* idx4 = (unsigned short*)(base + OFF_IDX4);
  int* list0 = (int*)(base + OFF_LIST0);
  int* list1 = (int*)(base + OFF_LIST1);
  int* list2 = (int*)(base + OFF_LIST2);
  int* list3 = (int*)(base + OFF_LIST3);
  int* list4 = (int*)(base + OFF_LIST4);
  float* h0 = (float*)(base + OFF_H0);
  float* h1 = (float*)(base + OFF_H1);
  float* h2 = (float*)(base + OFF_H2);
  float* h3 = (float*)(base + OFF_H3);
  float* h4 = (float*)(base + OFF_H4);
  float* h5 = (float*)(base + OFF_H5);

  // ---- P1: clear cnt/bn/fcomp, mark idx0, write coords ----
  {
    int gid = blk * NTHR + tid;  // 131072 threads
    if (gid < 2112) ((int4*)base)[gid] = make_int4(0, 0, 0, 0);
    if (gid < 15000) ((float4*)fcomp)[gid] = make_float4(0.f, 0.f, 0.f, 0.f);
    if (gid < NPTS) {
      const float* p = pc + (size_t)gid * 5;
      float fb = p[0], fx = p[1], fy = p[2], fz = p[3];
      ((float4*)out)[gid] = make_float4(fb, fx, fy, fz);
      int b = (int)fb, xx = (int)fx, yy = (int)fy, zz = (int)fz;
      int v = ((b * 128 + xx) * 128 + yy) * 128 + zz;
      idx0[v] = (unsigned short)MARKV;
    }
  }
  gsync(barb, 1, blk, tid);

  // ---- P2: compact level 0 (write-all; marks idx1 parents) ----
  cscan_phase<128, 512, 8, true>(blk, tid, idx0, list0, cnt, 0, idx1, smem);
  gsync(barb, 2, blk, tid);

  // ---- P3: compact level 1 (blocks 0..63)  ||  point-feature scatter ----
  if (blk < 64) {
    cscan_phase<64, 64, 8, true>(blk, tid, idx1, list1, cnt, 1, idx2, smem);
  } else {
    int i = (blk - 64) * NTHR + tid;
    if (i < NPTS) {
      const float* p = pc + (size_t)i * 5;
      int b = (int)p[0], xx = (int)p[1], yy = (int)p[2], zz = (int)p[3];
      float f = p[4];
      int v = ((b * 128 + xx) * 128 + yy) * 128 + zz;
      unsigned e = idx0[v];
      atomicAdd(&fcomp[e], f);
    }
  }
  gsync(barb, 3, blk, tid);

  // ---- P4: compact level 2 (blocks 0..15)  ||  submanifold conv + BN0 ----
  if (blk < 16) {
    cscan_phase<32, 16, 4, true>(blk, tid, idx2, list2, cnt, 2, idx3, smem);
  } else {
    float* wl = smem;         // 216
    float* sbn = smem + 216;  // 16
    for (int i = tid; i < 216; i += NTHR) wl[i] = wsub[i];
    if (tid < 16) sbn[tid] = 0.f;
    __syncthreads();
    int n0 = cnt[0];
    int ngrp = (n0 + 63) >> 6;  // 64 points per group (4 threads/point)
    int sub = tid & 3;
    int lane = tid & 63;
    for (int grp = blk - 16; grp < ngrp; grp += (NBLK - 16)) {
      int pid = grp * 64 + (tid >> 2);
      bool act = pid < n0;
      float acc[8] = {0, 0, 0, 0, 0, 0, 0, 0};
      if (act) {
        int v = list0[pid];
        int z = v & 127, y = (v >> 7) & 127, x = (v >> 14) & 127, b = v >> 21;
        int t0 = sub * 7, t1 = t0 + 7 > 27 ? 27 : t0 + 7;
        for (int t = t0; t < t1; t++) {
          int kd = t / 9, kh = (t / 3) % 3, kw = t % 3;
          int xx = x + kd - 1, yy = y + kh - 1, zz = z + kw - 1;
          if ((unsigned)xx < 128u && (unsigned)yy < 128u &&
              (unsigned)zz < 128u) {
            unsigned e = idx0[((b * 128 + xx) * 128 + yy) * 128 + zz];
            if (e != EMPTYV) {
              float val = fcomp[e];
#pragma unroll
              for (int o = 0; o < 8; o++)
                acc[o] = fmaf(val, wl[o * 27 + t], acc[o]);
            }
          }
        }
      }
#pragma unroll
      for (int o = 0; o < 8; o++) {  // combine the 4 tap-groups
        acc[o] += __shfl_xor(acc[o], 1, 64);
        acc[o] += __shfl_xor(acc[o], 2, 64);
      }
      if (act)
        ((float2*)(h0 + (size_t)pid * 8))[sub] =
            make_float2(acc[sub * 2], acc[sub * 2 + 1]);
#pragma unroll
      for (int o = 0; o < 8; o++) {  // each point counted once per channel
        float a = ((o >> 1) == sub && act) ? acc[o] : 0.f;
        float q = a * a;
#pragma unroll
        for (int off = 32; off > 0; off >>= 1) {
          a += __shfl_down(a, off, 64);
          q += __shfl_down(q, off, 64);
        }
        if (lane == 0) {
          atomicAdd(&sbn[o], a);
          atomicAdd(&sbn[8 + o], q);
        }
      }
    }
    __syncthreads();
    if (tid < 8) {
      int s = (blk & (NSLOT - 1)) * 64;
      atomicAdd(&bnsum[s + tid], sbn[tid]);
      atomicAdd(&bnss[s + tid], sbn[8 + tid]);
    }
  }
  gsync(barb, 4, blk, tid);

  // ---- P5: compact levels 3+4 (block 0)  ||  conv0 8->16 + BN1 ----
  if (blk == 0) {
    cscan_phase<16, 1, 8, true>(0, tid, idx3, list3, cnt, 3, idx4, smem);
    __syncthreads();
    cscan_phase<8, 1, 1, false>(0, tid, idx4, list4, cnt, 4,
                                (unsigned short*)0, smem);
  } else {
    conv_loop<8, 16, 16, 64, 0>(blk - 1, NBLK - 1, blk, tid, h0, idx0, list1,
                                cnt, 0, 1, w0, bnsum, bnss, g0, b0,
                                bnsum + 1024, bnss + 1024, h1, smem);
  }
  gsync(barb, 5, blk, tid);

  // ---- P6: conv1 16->32 + BN2 ----
  conv_loop<16, 32, 32, 32, 0>(blk, NBLK, blk, tid, h1, idx1, list2, cnt, 1, 2,
                               w1, bnsum + 1024, bnss + 1024, g1, b1,
                               bnsum + 2048, bnss + 2048, h2, smem);
  gsync(barb, 6, blk, tid);

  // ---- P7: conv2 32->64 + BN3 ----
  conv_loop<32, 64, 16, 16, 0>(blk, NBLK, blk, tid, h2, idx2, list3, cnt, 2, 3,
                               w2, bnsum + 2048, bnss + 2048, g2, b2,
                               bnsum + 3072, bnss + 3072, h3, smem);
  gsync(barb, 7, blk, tid);

  // ---- P8: conv3 64->128 dense ----
  conv_loop<64, 128, 8, 8, 1>(blk, NBLK, blk, tid, h3, idx3, list4, cnt, 3, 4,
                              w3, bnsum + 3072, bnss + 3072, g3, b3, (float*)0,
                              (float*)0, h4, smem);
  gsync(barb, 8, blk, tid);

  // ---- P9: masked max-pool 8^3 -> 4^3 ----
  {
    int item = blk * NTHR + tid;
    if (item < NB * 128 * 64) {
      int sp = item & 63;
      int c = (item >> 6) & 127;
      int b = item >> 13;
      int Z = sp & 3, Y = (sp >> 2) & 3, X = sp >> 4;
      float m = NEGF;
      int any = 0;
#pragma unroll
      for (int t = 0; t < 8; t++) {
        int kd = t >> 2, kh = (t >> 1) & 1, kw = t & 1;
        int csp = ((2 * X + kd) * 8 + 2 * Y + kh) * 8 + 2 * Z + kw;
        if (idx4[b * 512 + csp] != EMPTYV) {
          any = 1;
          m = fmaxf(m, h4[((size_t)b * 128 + c) * 512 + csp]);
        }
      }
      h5[((size_t)b * 128 + c) * 64 + sp] = any ? m : 0.f;
      if (c == 0) mask5[b * 64 + sp] = any;
    }
  }
  gsync(barb, 9, blk, tid);

  // ---- P10: pool 4^3 -> 2^3 + ReLU + linear (block 0) ----
  if (blk == 0) {
    float* h6s = smem;  // 2048
#pragma unroll
    for (int j = 0; j < 8; j++) {
      int e = tid * 8 + j;  // e = b*1024 + c*8 + sp
      int sp = e & 7, c = (e >> 3) & 127, b = e >> 10;
      int Z = sp & 1, Y = (sp >> 1) & 1, X = sp >> 2;
      float m = NEGF;
      int any = 0;
#pragma unroll
      for (int t = 0; t < 8; t++) {
        int kd = t >> 2, kh = (t >> 1) & 1, kw = t & 1;
        int csp = ((2 * X + kd) * 4 + 2 * Y + kh) * 4 + 2 * Z + kw;
        if (mask5[b * 64 + csp]) {
          any = 1;
          m = fmaxf(m, h5[((size_t)b * 128 + c) * 64 + csp]);
        }
      }
      h6s[e] = any ? fmaxf(m, 0.f) : 0.f;
    }
    __syncthreads();
    int wave = tid >> 6, lane = tid & 63;
    int b = wave >> 1, o = wave & 1;
    float s = 0.f;
    for (int k = lane; k < 1024; k += 64)
      s += h6s[b * 1024 + k] * Wc[o * 1024 + k];
#pragma unroll
    for (int off = 32; off > 0; off >>= 1) s += __shfl_down(s, off, 64);
    if (lane == 0) out[240000 + b * 2 + o] = s + bcv[o];
  }
}

// ---------------- host ----------------
extern "C" void kernel_launch(void* const* d_in, const int* in_sizes, int n_in,
                              void* d_out, int out_size, void* d_ws,
                              size_t ws_size, hipStream_t stream) {
  const float* pc = (const float*)d_in[0];
  const float* wsub = (const float*)d_in[1];
  const float* w0 = (const float*)d_in[2];
  const float* w1 = (const float*)d_in[3];
  const float* w2 = (const float*)d_in[4];
  const float* w3 = (const float*)d_in[5];
  const float* g0 = (const float*)d_in[6];
  const float* g1 = (const float*)d_in[7];
  const float* g2 = (const float*)d_in[8];
  const float* g3 = (const float*)d_in[9];
  const float* b0 = (const float*)d_in[10];
  const float* b1 = (const float*)d_in[11];
  const float* b2 = (const float*)d_in[12];
  const float* b3 = (const float*)d_in[13];
  const float* Wc = (const float*)d_in[14];
  const float* bc = (const float*)d_in[15];
  float* out = (float*)d_out;
  char* base = (char*)d_ws;

  hipMemsetAsync(base + OFF_BAR, 0, 28672, stream);  // barrier state
  // Guard: idx grids must start != MARKV (write-all scans fix them up).
  hipMemsetAsync(base + OFF_IDX0, 0xAA, OFF_LIST0 - OFF_IDX0, stream);

  k_all<<<dim3(NBLK), dim3(NTHR), 0, stream>>>(pc, wsub, w0, w1, w2, w3, g0, g1,
                                               g2, g3, b0, b1, b2, b3, Wc, bc,
                                               out, base);
}